// Round 2
// baseline (614.860 us; speedup 1.0000x reference)
//
#include <hip/hip_runtime.h>
#include <math.h>

#define Bsz 128
#define Tsz 256
#define Isz 256
#define Hsz 256
#define Lsz 4
#define Ssz 3
#define Mrows (Bsz*Tsz)   // 32768

using f16x8 = __attribute__((ext_vector_type(8))) _Float16;
using f32x4 = __attribute__((ext_vector_type(4))) float;

__device__ inline float fast_sig(float x) { return 1.f / (1.f + __expf(-x)); }
__device__ inline float fast_tanh(float x) {
  const float e = __expf(-2.f * fabsf(x));
  const float y = (1.f - e) / (1.f + e);
  return x < 0.f ? -y : y;
}

// ---------------- fp32 -> fp16 convert (8 elems/thread) ----------------
__global__ __launch_bounds__(256) void f32_to_f16(
    const float* __restrict__ src, _Float16* __restrict__ dst, int n8)
{
  const int idx = blockIdx.x * 256 + threadIdx.x;
  if (idx >= n8) return;
  const float4 v0 = *(const float4*)(src + (size_t)idx * 8);
  const float4 v1 = *(const float4*)(src + (size_t)idx * 8 + 4);
  _Float16 h[8];
  h[0] = (_Float16)v0.x; h[1] = (_Float16)v0.y;
  h[2] = (_Float16)v0.z; h[3] = (_Float16)v0.w;
  h[4] = (_Float16)v1.x; h[5] = (_Float16)v1.y;
  h[6] = (_Float16)v1.z; h[7] = (_Float16)v1.w;
  *(uint4*)(dst + (size_t)idx * 8) = *(uint4*)h;
}

// ---------------- fused GRU-layer GEMM, fp16 MFMA ----------------
// gi_slab = A @ W_slab^T (slabs r/z/n), gating fused, h written fp16.
// grid: (M/128, 256/64, 3 cur). block 256 = 4 waves.
// BK=32, double-buffered LDS (2x21KB = 42KB -> 3 blocks/CU), T3-minimum
// 2-phase pipeline: stage tile t+1 BEFORE compute of tile t; single
// __syncthreads per tile (its vmcnt(0) drain IS the pipeline wait).
__global__ __launch_bounds__(256, 3) void gemm_gru_f16(
    const _Float16* __restrict__ Abase, size_t a_cur_stride,
    const _Float16* __restrict__ Wbase, size_t w_cur_stride,
    const float* __restrict__ bi_g, size_t bi_stride,
    const float* __restrict__ bh_g, size_t bh_stride,
    _Float16* __restrict__ Hout)
{
  __shared__ _Float16 AhS[2][4 * 130 * 8];    // 2 x 8.3 KB
  __shared__ _Float16 WhS[2][12 * 66 * 8];    // 2 x 12.7 KB

  const int tid = threadIdx.x;
  const int cu  = blockIdx.z;
  const int m0  = blockIdx.x * 128;
  const int n0  = blockIdx.y * 64;

  const _Float16* A = Abase + (size_t)cu * a_cur_stride;
  const _Float16* W = Wbase + (size_t)cu * w_cur_stride;
  const float* bi = bi_g + (size_t)cu * bi_stride;
  const float* bh = bh_g + (size_t)cu * bh_stride;

  const int lane = tid & 63;
  const int wv   = tid >> 6;       // wave id 0..3 (uniform per wave)
  const int q    = lane >> 4;      // k-chunk within frag
  const int c    = lane & 15;      // row/col within frag
  const int mb   = wv * 32;        // wave's row base within 128-tile

  f32x4 acc[3][2][4];
  #pragma unroll
  for (int s = 0; s < 3; s++)
    #pragma unroll
    for (int mi = 0; mi < 2; mi++)
      #pragma unroll
      for (int ni = 0; ni < 4; ni++)
        acc[s][mi][ni] = (f32x4)0.f;

  // per-wave staging: wave wv stages A plane wv (2 halves) + W planes wv,wv+4,wv+8
  auto stage = [&](int buf, int k0) {
    const _Float16* ga = A + (size_t)(m0 + lane) * 256 + k0 + wv * 8;
    __builtin_amdgcn_global_load_lds(
        (const __attribute__((address_space(1))) void*)ga,
        (__attribute__((address_space(3))) void*)&AhS[buf][(wv * 130) * 8],
        16, 0, 0);
    __builtin_amdgcn_global_load_lds(
        (const __attribute__((address_space(1))) void*)(ga + 64 * 256),
        (__attribute__((address_space(3))) void*)&AhS[buf][(wv * 130 + 64) * 8],
        16, 0, 0);
    #pragma unroll
    for (int j = 0; j < 3; j++) {
      const int p = wv + j * 4;                 // plane 0..11
      const int s = p >> 2, ch = p & 3;
      __builtin_amdgcn_global_load_lds(
          (const __attribute__((address_space(1))) void*)
              (W + (size_t)(s * 256 + n0 + lane) * 256 + k0 + ch * 8),
          (__attribute__((address_space(3))) void*)&WhS[buf][(p * 66) * 8],
          16, 0, 0);
    }
  };

  auto compute = [&](int buf) {
    const f16x8 a0 = *(const f16x8*)&AhS[buf][(q * 130 + mb + c) * 8];
    const f16x8 a1 = *(const f16x8*)&AhS[buf][(q * 130 + mb + 16 + c) * 8];
    #pragma unroll
    for (int s = 0; s < 3; s++) {
      #pragma unroll
      for (int ni = 0; ni < 4; ni++) {
        const f16x8 w = *(const f16x8*)&WhS[buf][((s * 4 + q) * 66 + ni * 16 + c) * 8];
        acc[s][0][ni] = __builtin_amdgcn_mfma_f32_16x16x32_f16(a0, w, acc[s][0][ni], 0, 0, 0);
        acc[s][1][ni] = __builtin_amdgcn_mfma_f32_16x16x32_f16(a1, w, acc[s][1][ni], 0, 0, 0);
      }
    }
  };

  // prologue: stage tile 0, drain
  stage(0, 0);
  __syncthreads();

  // 2-phase main loop over 8 K-tiles of 32
  #pragma unroll
  for (int t = 0; t < 7; t++) {
    stage((t + 1) & 1, (t + 1) * 32);   // issue next tile's loads FIRST
    compute(t & 1);                     // ds_read + MFMA current tile
    __syncthreads();                    // vmcnt(0)+lgkmcnt(0)+barrier: next tile ready,
                                        // buffer reuse ordered
  }
  compute(1);                           // last tile (t=7), no further stage

  // epilogue: gating with fast native transcendentals, h stored fp16
  float bir[4], biz[4], bin_[4], bhr[4], bhz[4], bhn[4];
  #pragma unroll
  for (int ni = 0; ni < 4; ni++) {
    const int n = n0 + ni * 16 + c;
    bir[ni]  = bi[n];       bhr[ni] = bh[n];
    biz[ni]  = bi[256 + n]; bhz[ni] = bh[256 + n];
    bin_[ni] = bi[512 + n]; bhn[ni] = bh[512 + n];
  }
  #pragma unroll
  for (int mi = 0; mi < 2; mi++) {
    #pragma unroll
    for (int reg = 0; reg < 4; reg++) {
      const int m = m0 + mb + mi * 16 + q * 4 + reg;
      const size_t rowbase = ((size_t)cu * Mrows + m) * 256;
      #pragma unroll
      for (int ni = 0; ni < 4; ni++) {
        const float gr = acc[0][mi][ni][reg] + bir[ni] + bhr[ni];
        const float gz = acc[1][mi][ni][reg] + biz[ni] + bhz[ni];
        const float gn = acc[2][mi][ni][reg] + bin_[ni];
        const float r  = fast_sig(gr);
        const float zz = fast_sig(gz);
        const float nn = fast_tanh(gn + r * bhn[ni]);
        Hout[rowbase + n0 + ni * 16 + c] = (_Float16)((1.f - zz) * nn);
      }
    }
  }
}

// ---------------- per-layer dot products (e, p), block-tiled ----------------
// 64 rows/block; thread (r, pp) accumulates 7 dots over K-quarter pp in regs.
__global__ __launch_bounds__(256) void ep_tile(
    const _Float16* __restrict__ Hh,
    const float* __restrict__ w_lw, const float* __restrict__ w_sel, int layer,
    float* __restrict__ e, float* __restrict__ p)
{
  __shared__ _Float16 hs[64 * 264];   // 33 KB, padded stride
  __shared__ float wc[7][256];        // 7 KB
  __shared__ float ps[4][64][8];      // 8 KB partials
  const int tid = threadIdx.x;
  const size_t mg0 = (size_t)blockIdx.x * 64;

  // stage h tile (coalesced)
  #pragma unroll
  for (int i = 0; i < 8; i++) {
    const int ci = tid + i * 256;          // 0..2047 chunks of 16B
    const int row = ci >> 5, kc = ci & 31;
    *(uint4*)&hs[row * 264 + kc * 8] =
        *(const uint4*)(Hh + (mg0 + row) * 256 + kc * 8);
  }
  // stage weight block: rows 0-3 = w_lw, 4-6 = w_sel[:, 0:256]
  #pragma unroll
  for (int j = 0; j < 7; j++)
    wc[j][tid] = (j < 4) ? w_lw[j * 256 + tid] : w_sel[(j - 4) * 512 + tid];
  __syncthreads();

  const int r = tid & 63, pp = tid >> 6;
  float acc[7] = {0.f, 0.f, 0.f, 0.f, 0.f, 0.f, 0.f};
  #pragma unroll
  for (int i = 0; i < 8; i++) {
    union { uint4 u; _Float16 h[8]; } hv;
    hv.u = *(uint4*)&hs[r * 264 + pp * 64 + i * 8];
    float hf[8];
    #pragma unroll
    for (int k = 0; k < 8; k++) hf[k] = (float)hv.h[k];
    #pragma unroll
    for (int j = 0; j < 7; j++) {
      const float4 w0 = *(const float4*)&wc[j][pp * 64 + i * 8];
      const float4 w1 = *(const float4*)&wc[j][pp * 64 + i * 8 + 4];
      acc[j] += hf[0] * w0.x + hf[1] * w0.y + hf[2] * w0.z + hf[3] * w0.w
              + hf[4] * w1.x + hf[5] * w1.y + hf[6] * w1.z + hf[7] * w1.w;
    }
  }
  #pragma unroll
  for (int j = 0; j < 7; j++) ps[pp][r][j] = acc[j];
  __syncthreads();

  if (tid < 64) {
    float d[7];
    #pragma unroll
    for (int j = 0; j < 7; j++)
      d[j] = ps[0][tid][j] + ps[1][tid][j] + ps[2][tid][j] + ps[3][tid][j];
    const size_t mg = mg0 + tid;
    const int cc = (int)(mg >> 15);          // / Mrows
    const int m  = (int)(mg & 32767);
    const int b = m >> 8, t = m & 255;
    const size_t base = ((size_t)cc * Tsz + t) * Bsz + b;
    #pragma unroll
    for (int j = 0; j < 4; j++) e[base * 16 + layer * 4 + j] = d[j];
    #pragma unroll
    for (int j = 0; j < 3; j++) p[base * 12 + layer * 3 + j] = d[4 + j];
  }
}

// ---------------- softmax-attention + batch-reduced selector scores ----------------
__global__ __launch_bounds__(128) void attn_finish(
    const float* __restrict__ e, const float* __restrict__ p,
    const float* __restrict__ hidden, const float* __restrict__ b_lw,
    float* __restrict__ score_h)
{
  const int t = blockIdx.x, cc = blockIdx.y;
  const int b = threadIdx.x;
  const float* eb = e + ((size_t)(cc * Tsz + t) * Bsz + b) * 16;
  const float* pb = p + ((size_t)(cc * Tsz + t) * Bsz + b) * 12;
  const float* hb = hidden + b * 16;
  const float bl0 = b_lw[0], bl1 = b_lw[1], bl2 = b_lw[2], bl3 = b_lw[3];
  float attn[4];
  #pragma unroll
  for (int i = 0; i < 4; i++) {
    attn[i] = hb[i * 4 + 0] * (eb[i * 4 + 0] + bl0)
            + hb[i * 4 + 1] * (eb[i * 4 + 1] + bl1)
            + hb[i * 4 + 2] * (eb[i * 4 + 2] + bl2)
            + hb[i * 4 + 3] * (eb[i * 4 + 3] + bl3);
  }
  const float mx = fmaxf(fmaxf(attn[0], attn[1]), fmaxf(attn[2], attn[3]));
  float ex[4], sum = 0.f;
  #pragma unroll
  for (int i = 0; i < 4; i++) { ex[i] = expf(attn[i] - mx); sum += ex[i]; }
  const float inv = 1.f / sum;
  float sc[3];
  #pragma unroll
  for (int s = 0; s < 3; s++) {
    float v = 0.f;
    #pragma unroll
    for (int i = 0; i < 4; i++) v += ex[i] * pb[i * 3 + s];
    sc[s] = v * inv;
  }
  #pragma unroll
  for (int off = 32; off; off >>= 1)
    #pragma unroll
    for (int s = 0; s < 3; s++) sc[s] += __shfl_xor(sc[s], off);
  __shared__ float red[2][3];
  const int wv = threadIdx.x >> 6, ln = threadIdx.x & 63;
  if (ln == 0) { red[wv][0] = sc[0]; red[wv][1] = sc[1]; red[wv][2] = sc[2]; }
  __syncthreads();
  if (threadIdx.x == 0) {
    #pragma unroll
    for (int s = 0; s < 3; s++)
      score_h[((size_t)cc * Tsz + t) * 3 + s] = red[0][s] + red[1][s];
  }
}

// ---------------- xs[t,s] ----------------
__global__ __launch_bounds__(256) void xs_kernel(
    const float* __restrict__ x, const float* __restrict__ w_sel,
    const float* __restrict__ b_sel, float* __restrict__ xs)
{
  const int t = blockIdx.x, k = threadIdx.x;
  float s = 0.f;
  for (int b = 0; b < Bsz; b++) s += x[((size_t)b * Tsz + t) * Isz + k];
  float pr[3];
  #pragma unroll
  for (int qq = 0; qq < 3; qq++) pr[qq] = s * w_sel[qq * (Hsz + Isz) + Hsz + k];
  #pragma unroll
  for (int off = 32; off; off >>= 1)
    #pragma unroll
    for (int qq = 0; qq < 3; qq++) pr[qq] += __shfl_xor(pr[qq], off);
  __shared__ float red[4][3];
  const int wv = k >> 6, ln = k & 63;
  if (ln == 0) { red[wv][0] = pr[0]; red[wv][1] = pr[1]; red[wv][2] = pr[2]; }
  __syncthreads();
  if (k == 0) {
    #pragma unroll
    for (int qq = 0; qq < 3; qq++)
      xs[t * 3 + qq] = red[0][qq] + red[1][qq] + red[2][qq] + red[3][qq]
                      + (float)Bsz * b_sel[qq];
  }
}

// ---------------- serial selector chain ----------------
__global__ __launch_bounds__(256) void select_kernel(
    const float* __restrict__ score_h, const float* __restrict__ xs,
    int* __restrict__ cur)
{
  __shared__ int f[Tsz][3];
  const int tid = threadIdx.x;
  for (int u = tid; u < (Tsz - 1) * 3; u += 256) {
    const int t = 1 + u / 3, cc = u % 3;
    const float* sh = score_h + ((size_t)cc * Tsz + (t - 1)) * 3;
    const float* xr = xs + t * 3;
    const float v0 = sh[0] + xr[0];
    const float v1 = sh[1] + xr[1];
    const float v2 = sh[2] + xr[2];
    int best = 0; float bv = v0;
    if (v1 > bv) { bv = v1; best = 1; }
    if (v2 > bv) { bv = v2; best = 2; }
    f[t][cc] = best;
  }
  __syncthreads();
  if (tid == 0) {
    int cc = 0; cur[0] = 0;
    for (int t = 1; t < Tsz; t++) { cc = f[t][cc]; cur[t] = cc; }
  }
}

// ---------------- gather outputs (fp16 h -> fp32 out) ----------------
__global__ __launch_bounds__(256) void gather_out(
    const _Float16* __restrict__ Hh, const int* __restrict__ cur,
    float* __restrict__ out)
{
  const size_t idx = ((size_t)blockIdx.x * 256 + threadIdx.x) * 4;
  const size_t BTH = (size_t)Bsz * Tsz * Hsz;
  int b, t, h;
  if (idx < BTH) {
    b = (int)(idx >> 16);
    const int rem = (int)(idx & 65535);
    t = rem >> 8; h = rem & 255;
  } else {
    const size_t r2 = idx - BTH;
    b = (int)(r2 >> 8); h = (int)(r2 & 255); t = Tsz - 1;
  }
  const int cc = cur[t];
  const size_t g = (((size_t)cc * Mrows + (size_t)b * Tsz + t) * Hsz + h);
  union { ushort4 u; _Float16 hv[4]; } cv;
  cv.u = *(const ushort4*)(Hh + g);
  float4 v;
  v.x = (float)cv.hv[0]; v.y = (float)cv.hv[1];
  v.z = (float)cv.hv[2]; v.w = (float)cv.hv[3];
  *(float4*)(out + idx) = v;
}

extern "C" void kernel_launch(void* const* d_in, const int* in_sizes, int n_in,
                              void* d_out, int out_size, void* d_ws, size_t ws_size,
                              hipStream_t stream) {
  const float* x      = (const float*)d_in[0];
  const float* hidden = (const float*)d_in[1];
  const float* w_ih0  = (const float*)d_in[2];
  const float* b_ih0  = (const float*)d_in[3];
  const float* b_hh0  = (const float*)d_in[4];
  const float* w_ih   = (const float*)d_in[5];
  const float* b_ih   = (const float*)d_in[6];
  const float* b_hh   = (const float*)d_in[7];
  const float* w_lw   = (const float*)d_in[8];
  const float* b_lw   = (const float*)d_in[9];
  const float* w_sel  = (const float*)d_in[10];
  const float* b_sel  = (const float*)d_in[11];
  float* out = (float*)d_out;

  char* w = (char*)d_ws;
  const size_t HN = (size_t)3 * Mrows * 256;       // 25.2M
  const size_t XN = (size_t)Bsz * Tsz * Isz;       // 8.39M
  const size_t W0N = (size_t)3 * 768 * 256;        // 589824
  const size_t WLN = (size_t)3 * 3 * 768 * 256;    // 1769472
  _Float16* HA  = (_Float16*)w; w += HN * 2;
  _Float16* HB  = (_Float16*)w; w += HN * 2;
  _Float16* xh  = (_Float16*)w; w += XN * 2;
  _Float16* Wh0 = (_Float16*)w; w += W0N * 2;
  _Float16* WhL = (_Float16*)w; w += WLN * 2;
  float* e       = (float*)w; w += (size_t)3 * Tsz * Bsz * 16 * 4;
  float* p       = (float*)w; w += (size_t)3 * Tsz * Bsz * 12 * 4;
  float* score_h = (float*)w; w += (size_t)3 * Tsz * 3 * 4;
  float* xsb     = (float*)w; w += (size_t)Tsz * 3 * 4;
  int*   curb    = (int*)w;   w += (size_t)Tsz * 4;

  // fp32 -> fp16 conversions
  f32_to_f16<<<(int)(XN / 8 + 255) / 256, 256, 0, stream>>>(x, xh, (int)(XN / 8));
  f32_to_f16<<<(int)(W0N / 8 + 255) / 256, 256, 0, stream>>>(w_ih0, Wh0, (int)(W0N / 8));
  f32_to_f16<<<(int)(WLN / 8 + 255) / 256, 256, 0, stream>>>(w_ih, WhL, (int)(WLN / 8));

  dim3 ggrid(Mrows / 128, 4, 3);

  // layer 0: A = xh (shared across cur)
  gemm_gru_f16<<<ggrid, 256, 0, stream>>>(
      xh, (size_t)0, Wh0, (size_t)768 * 256,
      b_ih0, (size_t)768, b_hh0, (size_t)768, HA);
  ep_tile<<<(3 * Mrows) / 64, 256, 0, stream>>>(HA, w_lw, w_sel, 0, e, p);

  const size_t wcur = (size_t)3 * 768 * 256;
  const size_t bst  = (size_t)3 * 768;
  _Float16* ping = HA; _Float16* pong = HB;
  for (int l = 1; l < 4; l++) {
    gemm_gru_f16<<<ggrid, 256, 0, stream>>>(
        ping, (size_t)Mrows * 256,
        WhL + (size_t)(l - 1) * 768 * 256, wcur,
        b_ih + (size_t)(l - 1) * 768, bst,
        b_hh + (size_t)(l - 1) * 768, bst, pong);
    ep_tile<<<(3 * Mrows) / 64, 256, 0, stream>>>(pong, w_lw, w_sel, l, e, p);
    _Float16* t1 = ping; ping = pong; pong = t1;
  }

  attn_finish<<<dim3(Tsz, 3), 128, 0, stream>>>(e, p, hidden, b_lw, score_h);
  xs_kernel<<<Tsz, 256, 0, stream>>>(x, w_sel, b_sel, xsb);
  select_kernel<<<1, 256, 0, stream>>>(score_h, xsb, curb);
  gather_out<<<8224, 256, 0, stream>>>(ping, curb, out);
}

// Round 4
// 478.828 us; speedup vs baseline: 1.2841x; 1.2841x over previous
//
#include <hip/hip_runtime.h>
#include <math.h>

#define Bsz 128
#define Tsz 256
#define Isz 256
#define Hsz 256
#define Lsz 4
#define Ssz 3
#define Mrows (Bsz*Tsz)   // 32768

using f16x8 = __attribute__((ext_vector_type(8))) _Float16;
using f32x4 = __attribute__((ext_vector_type(4))) float;

__device__ inline float fast_sig(float x) { return 1.f / (1.f + __expf(-x)); }
__device__ inline float fast_tanh(float x) {
  const float e = __expf(-2.f * fabsf(x));
  const float y = (1.f - e) / (1.f + e);
  return x < 0.f ? -y : y;
}

// ---------------- fp32 -> fp16 convert (8 elems/thread) ----------------
__global__ __launch_bounds__(256) void f32_to_f16(
    const float* __restrict__ src, _Float16* __restrict__ dst, int n8)
{
  const int idx = blockIdx.x * 256 + threadIdx.x;
  if (idx >= n8) return;
  const float4 v0 = *(const float4*)(src + (size_t)idx * 8);
  const float4 v1 = *(const float4*)(src + (size_t)idx * 8 + 4);
  _Float16 h[8];
  h[0] = (_Float16)v0.x; h[1] = (_Float16)v0.y;
  h[2] = (_Float16)v0.z; h[3] = (_Float16)v0.w;
  h[4] = (_Float16)v1.x; h[5] = (_Float16)v1.y;
  h[6] = (_Float16)v1.z; h[7] = (_Float16)v1.w;
  *(uint4*)(dst + (size_t)idx * 8) = *(uint4*)h;
}

// ---------------- weight-stationary fused GRU-layer GEMM, fp16 MFMA ----------------
// Block owns (cur, 64-col n-tile). W frags (3 slabs x 8 k-blocks) live in
// registers, loaded ONCE (96 VGPRs/lane). Block streams M in 32-row chunks:
// A chunk (32 x 256 = 16 KB) double-buffered in LDS via global_load_lds,
// counted vmcnt(4) + raw barriers keep next chunk's loads in flight.
// Per chunk/wave: 48 MFMA, 16 ds_read_b128, fused gating epilogue.
// grid: (64 msegs of 512 rows, 4 n-tiles, 3 cur), block 256 = 4 waves.
__global__ __launch_bounds__(256, 3) void gemm_gru_f16(
    const _Float16* __restrict__ Abase, size_t a_cur_stride,
    const _Float16* __restrict__ Wbase, size_t w_cur_stride,
    const float* __restrict__ bi_g, size_t bi_stride,
    const float* __restrict__ bh_g, size_t bh_stride,
    _Float16* __restrict__ Hout)
{
  // A chunk buffers: 32 planes (pk = k0*4+q) x 32 rows x 16B, packed. 2 x 16 KB.
  __shared__ _Float16 AhS[2][8192];

  const int tid  = threadIdx.x;
  const int cu   = blockIdx.z;
  const int n0   = blockIdx.y * 64;
  const int rmb  = blockIdx.x * 512;       // this block's M range: 512 rows

  const _Float16* A = Abase + (size_t)cu * a_cur_stride;
  const _Float16* W = Wbase + (size_t)cu * w_cur_stride;
  const float* bi = bi_g + (size_t)cu * bi_stride;
  const float* bh = bh_g + (size_t)cu * bh_stride;

  const int lane = tid & 63;
  const int wv   = tid >> 6;       // wave id 0..3
  const int q    = lane >> 4;      // k-sub within frag (0..3)
  const int c    = lane & 15;      // row (A) / col (W,D) within frag

  // ---- load stationary W frags: wf[slab][k0], lane(q,c) = W[s*256+ncol][k0*32+q*8..+7]
  const int ncol = n0 + wv * 16 + c;
  f16x8 wf[3][8];
  #pragma unroll
  for (int s = 0; s < 3; s++)
    #pragma unroll
    for (int k0 = 0; k0 < 8; k0++)
      wf[s][k0] = *(const f16x8*)(W + (size_t)(s * 256 + ncol) * 256 + k0 * 32 + q * 8);

  // ---- biases (fixed column per lane)
  const float bir = bi[ncol],       bhr = bh[ncol];
  const float biz = bi[256 + ncol], bhz = bh[256 + ncol];
  const float bin_ = bi[512 + ncol], bhn = bh[512 + ncol];

  f32x4 acc[3][2];

  // ---- stage chunk (32 rows x 256 K) into buf: 16 x 1KB wave-instrs, 4/wave.
  // LDS linear: plane pk holds rows 0..31 of k-chunk [pk*8 .. pk*8+7].
  auto stage = [&](int buf, int ch) {
    const int rm = rmb + ch * 32;
    #pragma unroll
    for (int i = 0; i < 4; i++) {
      const int p0 = 8 * wv + 2 * i;                 // base plane (uniform)
      const int pk = p0 + (lane >> 5);               // this lane's plane
      const _Float16* src = A + (size_t)(rm + (lane & 31)) * 256 + pk * 8;
      __builtin_amdgcn_global_load_lds(
          (const __attribute__((address_space(1))) void*)src,
          (__attribute__((address_space(3))) void*)&AhS[buf][p0 * 256],
          16, 0, 0);
    }
  };

  // ---- compute + fused gating epilogue for one chunk
  auto compute_chunk = [&](int buf, int ch) {
    const int rm = rmb + ch * 32;
    #pragma unroll
    for (int s = 0; s < 3; s++)
      #pragma unroll
      for (int mi = 0; mi < 2; mi++)
        acc[s][mi] = (f32x4)0.f;
    #pragma unroll
    for (int k0 = 0; k0 < 8; k0++) {
      const f16x8 a0 = *(const f16x8*)&AhS[buf][(k0 * 4 + q) * 256 + c * 8];
      const f16x8 a1 = *(const f16x8*)&AhS[buf][(k0 * 4 + q) * 256 + 128 + c * 8];
      #pragma unroll
      for (int s = 0; s < 3; s++) {
        acc[s][0] = __builtin_amdgcn_mfma_f32_16x16x32_f16(a0, wf[s][k0], acc[s][0], 0, 0, 0);
        acc[s][1] = __builtin_amdgcn_mfma_f32_16x16x32_f16(a1, wf[s][k0], acc[s][1], 0, 0, 0);
      }
    }
    // gating epilogue: row = rm + mi*16 + q*4 + reg, col = ncol
    #pragma unroll
    for (int mi = 0; mi < 2; mi++) {
      #pragma unroll
      for (int reg = 0; reg < 4; reg++) {
        const float gr = acc[0][mi][reg] + bir + bhr;
        const float gz = acc[1][mi][reg] + biz + bhz;
        const float gn = acc[2][mi][reg] + bin_;
        const float r  = fast_sig(gr);
        const float zz = fast_sig(gz);
        const float nn = fast_tanh(gn + r * bhn);
        const size_t row = (size_t)cu * Mrows + rm + mi * 16 + q * 4 + reg;
        Hout[row * 256 + ncol] = (_Float16)((1.f - zz) * nn);
      }
    }
  };

  // ---- prologue
  stage(0, 0);

  // ---- main loop over 16 chunks, 2-buffer pipeline with counted vmcnt.
  // vmcnt(4) right after the 4 just-issued stage ops: waits everything older
  // (incl. prev chunk's stage + prev epilogue stores) -> never under-waits.
  for (int t = 0; t < 15; ++t) {
    stage((t + 1) & 1, t + 1);
    __builtin_amdgcn_sched_barrier(0);
    asm volatile("s_waitcnt vmcnt(4)" ::: "memory");
    __builtin_amdgcn_s_barrier();
    __builtin_amdgcn_sched_barrier(0);
    compute_chunk(t & 1, t);
    __builtin_amdgcn_sched_barrier(0);
    __builtin_amdgcn_s_barrier();      // all reads of buf[t&1] done before t+2 stages it
  }
  asm volatile("s_waitcnt vmcnt(0)" ::: "memory");
  __builtin_amdgcn_s_barrier();
  compute_chunk(1, 15);
}

// ---------------- per-layer dot products (e, p), block-tiled ----------------
// 64 rows/block; thread (r, pp) accumulates 7 dots over K-quarter pp in regs.
__global__ __launch_bounds__(256) void ep_tile(
    const _Float16* __restrict__ Hh,
    const float* __restrict__ w_lw, const float* __restrict__ w_sel, int layer,
    float* __restrict__ e, float* __restrict__ p)
{
  __shared__ _Float16 hs[64 * 264];   // 33 KB, padded stride
  __shared__ float wc[7][256];        // 7 KB
  __shared__ float ps[4][64][8];      // 8 KB partials
  const int tid = threadIdx.x;
  const size_t mg0 = (size_t)blockIdx.x * 64;

  // stage h tile (coalesced)
  #pragma unroll
  for (int i = 0; i < 8; i++) {
    const int ci = tid + i * 256;          // 0..2047 chunks of 16B
    const int row = ci >> 5, kc = ci & 31;
    *(uint4*)&hs[row * 264 + kc * 8] =
        *(const uint4*)(Hh + (mg0 + row) * 256 + kc * 8);
  }
  // stage weight block: rows 0-3 = w_lw, 4-6 = w_sel[:, 0:256]
  #pragma unroll
  for (int j = 0; j < 7; j++)
    wc[j][tid] = (j < 4) ? w_lw[j * 256 + tid] : w_sel[(j - 4) * 512 + tid];
  __syncthreads();

  const int r = tid & 63, pp = tid >> 6;
  float acc[7] = {0.f, 0.f, 0.f, 0.f, 0.f, 0.f, 0.f};
  #pragma unroll
  for (int i = 0; i < 8; i++) {
    union { uint4 u; _Float16 h[8]; } hv;
    hv.u = *(uint4*)&hs[r * 264 + pp * 64 + i * 8];
    float hf[8];
    #pragma unroll
    for (int k = 0; k < 8; k++) hf[k] = (float)hv.h[k];
    #pragma unroll
    for (int j = 0; j < 7; j++) {
      const float4 w0 = *(const float4*)&wc[j][pp * 64 + i * 8];
      const float4 w1 = *(const float4*)&wc[j][pp * 64 + i * 8 + 4];
      acc[j] += hf[0] * w0.x + hf[1] * w0.y + hf[2] * w0.z + hf[3] * w0.w
              + hf[4] * w1.x + hf[5] * w1.y + hf[6] * w1.z + hf[7] * w1.w;
    }
  }
  #pragma unroll
  for (int j = 0; j < 7; j++) ps[pp][r][j] = acc[j];
  __syncthreads();

  if (tid < 64) {
    float d[7];
    #pragma unroll
    for (int j = 0; j < 7; j++)
      d[j] = ps[0][tid][j] + ps[1][tid][j] + ps[2][tid][j] + ps[3][tid][j];
    const size_t mg = mg0 + tid;
    const int cc = (int)(mg >> 15);          // / Mrows
    const int m  = (int)(mg & 32767);
    const int b = m >> 8, t = m & 255;
    const size_t base = ((size_t)cc * Tsz + t) * Bsz + b;
    #pragma unroll
    for (int j = 0; j < 4; j++) e[base * 16 + layer * 4 + j] = d[j];
    #pragma unroll
    for (int j = 0; j < 3; j++) p[base * 12 + layer * 3 + j] = d[4 + j];
  }
}

// ---------------- softmax-attention + batch-reduced selector scores ----------------
__global__ __launch_bounds__(128) void attn_finish(
    const float* __restrict__ e, const float* __restrict__ p,
    const float* __restrict__ hidden, const float* __restrict__ b_lw,
    float* __restrict__ score_h)
{
  const int t = blockIdx.x, cc = blockIdx.y;
  const int b = threadIdx.x;
  const float* eb = e + ((size_t)(cc * Tsz + t) * Bsz + b) * 16;
  const float* pb = p + ((size_t)(cc * Tsz + t) * Bsz + b) * 12;
  const float* hb = hidden + b * 16;
  const float bl0 = b_lw[0], bl1 = b_lw[1], bl2 = b_lw[2], bl3 = b_lw[3];
  float attn[4];
  #pragma unroll
  for (int i = 0; i < 4; i++) {
    attn[i] = hb[i * 4 + 0] * (eb[i * 4 + 0] + bl0)
            + hb[i * 4 + 1] * (eb[i * 4 + 1] + bl1)
            + hb[i * 4 + 2] * (eb[i * 4 + 2] + bl2)
            + hb[i * 4 + 3] * (eb[i * 4 + 3] + bl3);
  }
  const float mx = fmaxf(fmaxf(attn[0], attn[1]), fmaxf(attn[2], attn[3]));
  float ex[4], sum = 0.f;
  #pragma unroll
  for (int i = 0; i < 4; i++) { ex[i] = expf(attn[i] - mx); sum += ex[i]; }
  const float inv = 1.f / sum;
  float sc[3];
  #pragma unroll
  for (int s = 0; s < 3; s++) {
    float v = 0.f;
    #pragma unroll
    for (int i = 0; i < 4; i++) v += ex[i] * pb[i * 3 + s];
    sc[s] = v * inv;
  }
  #pragma unroll
  for (int off = 32; off; off >>= 1)
    #pragma unroll
    for (int s = 0; s < 3; s++) sc[s] += __shfl_xor(sc[s], off);
  __shared__ float red[2][3];
  const int wv = threadIdx.x >> 6, ln = threadIdx.x & 63;
  if (ln == 0) { red[wv][0] = sc[0]; red[wv][1] = sc[1]; red[wv][2] = sc[2]; }
  __syncthreads();
  if (threadIdx.x == 0) {
    #pragma unroll
    for (int s = 0; s < 3; s++)
      score_h[((size_t)cc * Tsz + t) * 3 + s] = red[0][s] + red[1][s];
  }
}

// ---------------- xs[t,s] ----------------
__global__ __launch_bounds__(256) void xs_kernel(
    const float* __restrict__ x, const float* __restrict__ w_sel,
    const float* __restrict__ b_sel, float* __restrict__ xs)
{
  const int t = blockIdx.x, k = threadIdx.x;
  float s = 0.f;
  for (int b = 0; b < Bsz; b++) s += x[((size_t)b * Tsz + t) * Isz + k];
  float pr[3];
  #pragma unroll
  for (int qq = 0; qq < 3; qq++) pr[qq] = s * w_sel[qq * (Hsz + Isz) + Hsz + k];
  #pragma unroll
  for (int off = 32; off; off >>= 1)
    #pragma unroll
    for (int qq = 0; qq < 3; qq++) pr[qq] += __shfl_xor(pr[qq], off);
  __shared__ float red[4][3];
  const int wv = k >> 6, ln = k & 63;
  if (ln == 0) { red[wv][0] = pr[0]; red[wv][1] = pr[1]; red[wv][2] = pr[2]; }
  __syncthreads();
  if (k == 0) {
    #pragma unroll
    for (int qq = 0; qq < 3; qq++)
      xs[t * 3 + qq] = red[0][qq] + red[1][qq] + red[2][qq] + red[3][qq]
                      + (float)Bsz * b_sel[qq];
  }
}

// ---------------- serial selector chain ----------------
__global__ __launch_bounds__(256) void select_kernel(
    const float* __restrict__ score_h, const float* __restrict__ xs,
    int* __restrict__ cur)
{
  __shared__ int f[Tsz][3];
  const int tid = threadIdx.x;
  for (int u = tid; u < (Tsz - 1) * 3; u += 256) {
    const int t = 1 + u / 3, cc = u % 3;
    const float* sh = score_h + ((size_t)cc * Tsz + (t - 1)) * 3;
    const float* xr = xs + t * 3;
    const float v0 = sh[0] + xr[0];
    const float v1 = sh[1] + xr[1];
    const float v2 = sh[2] + xr[2];
    int best = 0; float bv = v0;
    if (v1 > bv) { bv = v1; best = 1; }
    if (v2 > bv) { bv = v2; best = 2; }
    f[t][cc] = best;
  }
  __syncthreads();
  if (tid == 0) {
    int cc = 0; cur[0] = 0;
    for (int t = 1; t < Tsz; t++) { cc = f[t][cc]; cur[t] = cc; }
  }
}

// ---------------- gather outputs (fp16 h -> fp32 out) ----------------
__global__ __launch_bounds__(256) void gather_out(
    const _Float16* __restrict__ Hh, const int* __restrict__ cur,
    float* __restrict__ out)
{
  const size_t idx = ((size_t)blockIdx.x * 256 + threadIdx.x) * 4;
  const size_t BTH = (size_t)Bsz * Tsz * Hsz;
  int b, t, h;
  if (idx < BTH) {
    b = (int)(idx >> 16);
    const int rem = (int)(idx & 65535);
    t = rem >> 8; h = rem & 255;
  } else {
    const size_t r2 = idx - BTH;
    b = (int)(r2 >> 8); h = (int)(r2 & 255); t = Tsz - 1;
  }
  const int cc = cur[t];
  const size_t g = (((size_t)cc * Mrows + (size_t)b * Tsz + t) * Hsz + h);
  union { ushort4 u; _Float16 hv[4]; } cv;
  cv.u = *(const ushort4*)(Hh + g);
  float4 v;
  v.x = (float)cv.hv[0]; v.y = (float)cv.hv[1];
  v.z = (float)cv.hv[2]; v.w = (float)cv.hv[3];
  *(float4*)(out + idx) = v;
}

extern "C" void kernel_launch(void* const* d_in, const int* in_sizes, int n_in,
                              void* d_out, int out_size, void* d_ws, size_t ws_size,
                              hipStream_t stream) {
  const float* x      = (const float*)d_in[0];
  const float* hidden = (const float*)d_in[1];
  const float* w_ih0  = (const float*)d_in[2];
  const float* b_ih0  = (const float*)d_in[3];
  const float* b_hh0  = (const float*)d_in[4];
  const float* w_ih   = (const float*)d_in[5];
  const float* b_ih   = (const float*)d_in[6];
  const float* b_hh   = (const float*)d_in[7];
  const float* w_lw   = (const float*)d_in[8];
  const float* b_lw   = (const float*)d_in[9];
  const float* w_sel  = (const float*)d_in[10];
  const float* b_sel  = (const float*)d_in[11];
  float* out = (float*)d_out;

  char* w = (char*)d_ws;
  const size_t HN = (size_t)3 * Mrows * 256;       // 25.2M
  const size_t XN = (size_t)Bsz * Tsz * Isz;       // 8.39M
  const size_t W0N = (size_t)3 * 768 * 256;        // 589824
  const size_t WLN = (size_t)3 * 3 * 768 * 256;    // 1769472
  _Float16* HA  = (_Float16*)w; w += HN * 2;
  _Float16* HB  = (_Float16*)w; w += HN * 2;
  _Float16* xh  = (_Float16*)w; w += XN * 2;
  _Float16* Wh0 = (_Float16*)w; w += W0N * 2;
  _Float16* WhL = (_Float16*)w; w += WLN * 2;
  float* e       = (float*)w; w += (size_t)3 * Tsz * Bsz * 16 * 4;
  float* p       = (float*)w; w += (size_t)3 * Tsz * Bsz * 12 * 4;
  float* score_h = (float*)w; w += (size_t)3 * Tsz * 3 * 4;
  float* xsb     = (float*)w; w += (size_t)Tsz * 3 * 4;
  int*   curb    = (int*)w;   w += (size_t)Tsz * 4;

  // fp32 -> fp16 conversions
  f32_to_f16<<<(int)(XN / 8 + 255) / 256, 256, 0, stream>>>(x, xh, (int)(XN / 8));
  f32_to_f16<<<(int)(W0N / 8 + 255) / 256, 256, 0, stream>>>(w_ih0, Wh0, (int)(W0N / 8));
  f32_to_f16<<<(int)(WLN / 8 + 255) / 256, 256, 0, stream>>>(w_ih, WhL, (int)(WLN / 8));

  // weight-stationary GEMM grid: (mseg, n-tile, cur)
  dim3 ggrid(64, 4, 3);

  // layer 0: A = xh (shared across cur)
  gemm_gru_f16<<<ggrid, 256, 0, stream>>>(
      xh, (size_t)0, Wh0, (size_t)768 * 256,
      b_ih0, (size_t)768, b_hh0, (size_t)768, HA);
  ep_tile<<<(3 * Mrows) / 64, 256, 0, stream>>>(HA, w_lw, w_sel, 0, e, p);

  const size_t wcur = (size_t)3 * 768 * 256;
  const size_t bst  = (size_t)3 * 768;
  _Float16* ping = HA; _Float16* pong = HB;
  for (int l = 1; l < 4; l++) {
    gemm_gru_f16<<<ggrid, 256, 0, stream>>>(
        ping, (size_t)Mrows * 256,
        WhL + (size_t)(l - 1) * 768 * 256, wcur,
        b_ih + (size_t)(l - 1) * 768, bst,
        b_hh + (size_t)(l - 1) * 768, bst, pong);
    ep_tile<<<(3 * Mrows) / 64, 256, 0, stream>>>(pong, w_lw, w_sel, l, e, p);
    _Float16* t1 = ping; ping = pong; pong = t1;
  }

  attn_finish<<<dim3(Tsz, 3), 128, 0, stream>>>(e, p, hidden, b_lw, score_h);
  xs_kernel<<<Tsz, 256, 0, stream>>>(x, w_sel, b_sel, xsb);
  select_kernel<<<1, 256, 0, stream>>>(score_h, xsb, curb);
  gather_out<<<8224, 256, 0, stream>>>(ping, curb, out);
}

// Round 5
// 404.077 us; speedup vs baseline: 1.5216x; 1.1850x over previous
//
#include <hip/hip_runtime.h>
#include <math.h>

#define Bsz 128
#define Tsz 256
#define Isz 256
#define Hsz 256
#define Lsz 4
#define Ssz 3
#define Mrows (Bsz*Tsz)   // 32768

using f16x8 = __attribute__((ext_vector_type(8))) _Float16;
using f32x4 = __attribute__((ext_vector_type(4))) float;

#define LOG2E 1.44269504f

// ---------------- fp32 -> fp16 convert (8 elems/thread) ----------------
__global__ __launch_bounds__(256) void f32_to_f16(
    const float* __restrict__ src, _Float16* __restrict__ dst, int n8)
{
  const int idx = blockIdx.x * 256 + threadIdx.x;
  if (idx >= n8) return;
  const float4 v0 = *(const float4*)(src + (size_t)idx * 8);
  const float4 v1 = *(const float4*)(src + (size_t)idx * 8 + 4);
  _Float16 h[8];
  h[0] = (_Float16)v0.x; h[1] = (_Float16)v0.y;
  h[2] = (_Float16)v0.z; h[3] = (_Float16)v0.w;
  h[4] = (_Float16)v1.x; h[5] = (_Float16)v1.y;
  h[6] = (_Float16)v1.z; h[7] = (_Float16)v1.w;
  *(uint4*)(dst + (size_t)idx * 8) = *(uint4*)h;
}

// ---------------- weight-stationary fused GRU-layer GEMM, fp16 MFMA ----------------
// Block owns (cur, 64-col n-tile). W frags pinned in registers (96 VGPR/lane,
// asm-pinned; launch_bounds(256,2) so no spill). Streams M in 32-row chunks:
// A chunk (16 KB) in a 3-buffer LDS ring via global_load_lds, 2-deep prefetch,
// ONE barrier + exact counted vmcnt(12) per chunk (12 = 4 stage + 8 stores;
// 2B stores at 512B stride can never merge, so the count is stable).
// Gating epilogue: 3 v_exp + 2 v_rcp per output, biases pre-folded, no divs.
__global__ __launch_bounds__(256, 2) void gemm_gru_f16(
    const _Float16* __restrict__ Abase, size_t a_cur_stride,
    const _Float16* __restrict__ Wbase, size_t w_cur_stride,
    const float* __restrict__ bi_g, size_t bi_stride,
    const float* __restrict__ bh_g, size_t bh_stride,
    _Float16* __restrict__ Hout)
{
  // 3 x 16 KB ring: 32 planes (pk = k0*4+q) x 32 rows x 16B each.
  __shared__ _Float16 AhS[3][8192];

  const int tid  = threadIdx.x;
  const int cu   = blockIdx.z;
  const int n0   = blockIdx.y * 64;
  const int rmb  = blockIdx.x * 512;       // this block's M range: 512 rows

  const _Float16* A = Abase + (size_t)cu * a_cur_stride;
  const _Float16* W = Wbase + (size_t)cu * w_cur_stride;
  const float* bi = bi_g + (size_t)cu * bi_stride;
  const float* bh = bh_g + (size_t)cu * bh_stride;

  const int lane = tid & 63;
  const int wv   = tid >> 6;       // wave id 0..3
  const int q    = lane >> 4;      // k-sub within frag (0..3)
  const int c    = lane & 15;      // row (A) / col (W,D) within frag

  // ---- load stationary W frags: wf[slab][k0], lane(q,c) = W[s*256+ncol][k0*32+q*8..+7]
  const int ncol = n0 + wv * 16 + c;
  f16x8 wf[3][8];
  #pragma unroll
  for (int s = 0; s < 3; s++)
    #pragma unroll
    for (int k0 = 0; k0 < 8; k0++)
      wf[s][k0] = *(const f16x8*)(W + (size_t)(s * 256 + ncol) * 256 + k0 * 32 + q * 8);
  // pin: force wf to live in VGPRs once; defeats rematerialization into the loop
  #pragma unroll
  for (int s = 0; s < 3; s++)
    #pragma unroll
    for (int k0 = 0; k0 < 8; k0++)
      asm volatile("" : "+v"(wf[s][k0]));

  // ---- biases folded into exp2 arguments (per-lane constants)
  // r  = sig(ar + bir + bhr)      -> e0 = exp2(-L2E*ar + c0), r = rcp(1+e0)
  // 1-z = 1/(1+exp(az + biz+bhz)) -> e1 = exp2( L2E*az + c1)
  // n  = tanh(an + bin + r*bhn)   -> e2 = exp2(2*L2E*(an + r*bhn) + c3)
  //      out = (e2-1) * rcp((1+e1)*(1+e2))
  const float c0  = -LOG2E * (bi[ncol] + bh[ncol]);
  const float c1  =  LOG2E * (bi[256 + ncol] + bh[256 + ncol]);
  const float c3  = 2.f * LOG2E * bi[512 + ncol];
  const float bhn = bh[512 + ncol];

  f32x4 acc[3][2];

  // ---- stage chunk (32 rows x 256 K) into buf: 16 x 1KB wave-instrs, 4/wave.
  auto stage = [&](int buf, int ch) {
    const int rm = rmb + ch * 32;
    #pragma unroll
    for (int i = 0; i < 4; i++) {
      const int p0 = 8 * wv + 2 * i;                 // base plane (uniform)
      const int pk = p0 + (lane >> 5);               // this lane's plane
      const _Float16* src = A + (size_t)(rm + (lane & 31)) * 256 + pk * 8;
      __builtin_amdgcn_global_load_lds(
          (const __attribute__((address_space(1))) void*)src,
          (__attribute__((address_space(3))) void*)&AhS[buf][p0 * 256],
          16, 0, 0);
    }
  };

  // ---- compute + fused gating epilogue for one chunk (8 outputs/lane)
  auto compute_chunk = [&](int buf, int ch) {
    const int rm = rmb + ch * 32;
    #pragma unroll
    for (int s = 0; s < 3; s++)
      #pragma unroll
      for (int mi = 0; mi < 2; mi++)
        acc[s][mi] = (f32x4)0.f;
    #pragma unroll
    for (int k0 = 0; k0 < 8; k0++) {
      const f16x8 a0 = *(const f16x8*)&AhS[buf][(k0 * 4 + q) * 256 + c * 8];
      const f16x8 a1 = *(const f16x8*)&AhS[buf][(k0 * 4 + q) * 256 + 128 + c * 8];
      #pragma unroll
      for (int s = 0; s < 3; s++) {
        acc[s][0] = __builtin_amdgcn_mfma_f32_16x16x32_f16(a0, wf[s][k0], acc[s][0], 0, 0, 0);
        acc[s][1] = __builtin_amdgcn_mfma_f32_16x16x32_f16(a1, wf[s][k0], acc[s][1], 0, 0, 0);
      }
    }
    #pragma unroll
    for (int mi = 0; mi < 2; mi++) {
      #pragma unroll
      for (int reg = 0; reg < 4; reg++) {
        const float ar = acc[0][mi][reg];
        const float az = acc[1][mi][reg];
        const float an = acc[2][mi][reg];
        const float e0 = __builtin_amdgcn_exp2f(fmaf(-LOG2E, ar, c0));
        const float r  = __builtin_amdgcn_rcpf(1.f + e0);
        const float e1 = __builtin_amdgcn_exp2f(fmaf(LOG2E, az, c1));
        const float tt = fmaf(r, bhn, an);
        const float a2 = fminf(fmaf(2.f * LOG2E, tt, c3), 120.f);
        const float e2 = __builtin_amdgcn_exp2f(a2);
        const float out = (e2 - 1.f) *
            __builtin_amdgcn_rcpf((1.f + e1) * (1.f + e2));
        const size_t row = (size_t)cu * Mrows + rm + mi * 16 + q * 4 + reg;
        Hout[row * 256 + ncol] = (_Float16)out;
      }
    }
  };

  // ---- prologue: 2 chunks in flight, drain chunk 0
  stage(0, 0);
  stage(1, 1);
  asm volatile("s_waitcnt vmcnt(4)" ::: "memory");
  __builtin_amdgcn_s_barrier();

  // ---- main loop: {stage(t+2) || compute(t)}, one barrier/chunk.
  // vmcnt(12) leaves exactly this iter's 12 vmem ops (4 stage + 8 stores)
  // outstanding -> drains stage(t+1), ready for compute(t+1) after barrier.
  int bc = 0;
  for (int t = 0; t < 14; ++t) {
    int bs = bc + 2; if (bs >= 3) bs -= 3;
    stage(bs, t + 2);
    compute_chunk(bc, t);
    asm volatile("s_waitcnt vmcnt(12)" ::: "memory");
    __builtin_amdgcn_s_barrier();
    bc = (bc + 1 == 3) ? 0 : bc + 1;
  }
  compute_chunk(bc, 14);                 // bc = 2 = 14%3
  asm volatile("s_waitcnt vmcnt(0)" ::: "memory");
  __builtin_amdgcn_s_barrier();
  bc = (bc + 1 == 3) ? 0 : bc + 1;       // = 0 = 15%3
  compute_chunk(bc, 15);
}

// ---------------- per-layer dot products (e, p), block-tiled ----------------
// 64 rows/block; thread (r, pp) accumulates 7 dots over K-quarter pp in regs.
__global__ __launch_bounds__(256) void ep_tile(
    const _Float16* __restrict__ Hh,
    const float* __restrict__ w_lw, const float* __restrict__ w_sel, int layer,
    float* __restrict__ e, float* __restrict__ p)
{
  __shared__ _Float16 hs[64 * 264];   // 33 KB, padded stride
  __shared__ float wc[7][256];        // 7 KB
  __shared__ float ps[4][64][8];      // 8 KB partials
  const int tid = threadIdx.x;
  const size_t mg0 = (size_t)blockIdx.x * 64;

  // stage h tile (coalesced)
  #pragma unroll
  for (int i = 0; i < 8; i++) {
    const int ci = tid + i * 256;          // 0..2047 chunks of 16B
    const int row = ci >> 5, kc = ci & 31;
    *(uint4*)&hs[row * 264 + kc * 8] =
        *(const uint4*)(Hh + (mg0 + row) * 256 + kc * 8);
  }
  // stage weight block: rows 0-3 = w_lw, 4-6 = w_sel[:, 0:256]
  #pragma unroll
  for (int j = 0; j < 7; j++)
    wc[j][tid] = (j < 4) ? w_lw[j * 256 + tid] : w_sel[(j - 4) * 512 + tid];
  __syncthreads();

  const int r = tid & 63, pp = tid >> 6;
  float acc[7] = {0.f, 0.f, 0.f, 0.f, 0.f, 0.f, 0.f};
  #pragma unroll
  for (int i = 0; i < 8; i++) {
    union { uint4 u; _Float16 h[8]; } hv;
    hv.u = *(uint4*)&hs[r * 264 + pp * 64 + i * 8];
    float hf[8];
    #pragma unroll
    for (int k = 0; k < 8; k++) hf[k] = (float)hv.h[k];
    #pragma unroll
    for (int j = 0; j < 7; j++) {
      const float4 w0 = *(const float4*)&wc[j][pp * 64 + i * 8];
      const float4 w1 = *(const float4*)&wc[j][pp * 64 + i * 8 + 4];
      acc[j] += hf[0] * w0.x + hf[1] * w0.y + hf[2] * w0.z + hf[3] * w0.w
              + hf[4] * w1.x + hf[5] * w1.y + hf[6] * w1.z + hf[7] * w1.w;
    }
  }
  #pragma unroll
  for (int j = 0; j < 7; j++) ps[pp][r][j] = acc[j];
  __syncthreads();

  if (tid < 64) {
    float d[7];
    #pragma unroll
    for (int j = 0; j < 7; j++)
      d[j] = ps[0][tid][j] + ps[1][tid][j] + ps[2][tid][j] + ps[3][tid][j];
    const size_t mg = mg0 + tid;
    const int cc = (int)(mg >> 15);          // / Mrows
    const int m  = (int)(mg & 32767);
    const int b = m >> 8, t = m & 255;
    const size_t base = ((size_t)cc * Tsz + t) * Bsz + b;
    #pragma unroll
    for (int j = 0; j < 4; j++) e[base * 16 + layer * 4 + j] = d[j];
    #pragma unroll
    for (int j = 0; j < 3; j++) p[base * 12 + layer * 3 + j] = d[4 + j];
  }
}

// ---------------- softmax-attention + batch-reduced selector scores ----------------
__global__ __launch_bounds__(128) void attn_finish(
    const float* __restrict__ e, const float* __restrict__ p,
    const float* __restrict__ hidden, const float* __restrict__ b_lw,
    float* __restrict__ score_h)
{
  const int t = blockIdx.x, cc = blockIdx.y;
  const int b = threadIdx.x;
  const float* eb = e + ((size_t)(cc * Tsz + t) * Bsz + b) * 16;
  const float* pb = p + ((size_t)(cc * Tsz + t) * Bsz + b) * 12;
  const float* hb = hidden + b * 16;
  const float bl0 = b_lw[0], bl1 = b_lw[1], bl2 = b_lw[2], bl3 = b_lw[3];
  float attn[4];
  #pragma unroll
  for (int i = 0; i < 4; i++) {
    attn[i] = hb[i * 4 + 0] * (eb[i * 4 + 0] + bl0)
            + hb[i * 4 + 1] * (eb[i * 4 + 1] + bl1)
            + hb[i * 4 + 2] * (eb[i * 4 + 2] + bl2)
            + hb[i * 4 + 3] * (eb[i * 4 + 3] + bl3);
  }
  const float mx = fmaxf(fmaxf(attn[0], attn[1]), fmaxf(attn[2], attn[3]));
  float ex[4], sum = 0.f;
  #pragma unroll
  for (int i = 0; i < 4; i++) { ex[i] = expf(attn[i] - mx); sum += ex[i]; }
  const float inv = 1.f / sum;
  float sc[3];
  #pragma unroll
  for (int s = 0; s < 3; s++) {
    float v = 0.f;
    #pragma unroll
    for (int i = 0; i < 4; i++) v += ex[i] * pb[i * 3 + s];
    sc[s] = v * inv;
  }
  #pragma unroll
  for (int off = 32; off; off >>= 1)
    #pragma unroll
    for (int s = 0; s < 3; s++) sc[s] += __shfl_xor(sc[s], off);
  __shared__ float red[2][3];
  const int wv = threadIdx.x >> 6, ln = threadIdx.x & 63;
  if (ln == 0) { red[wv][0] = sc[0]; red[wv][1] = sc[1]; red[wv][2] = sc[2]; }
  __syncthreads();
  if (threadIdx.x == 0) {
    #pragma unroll
    for (int s = 0; s < 3; s++)
      score_h[((size_t)cc * Tsz + t) * 3 + s] = red[0][s] + red[1][s];
  }
}

// ---------------- xs[t,s] ----------------
__global__ __launch_bounds__(256) void xs_kernel(
    const float* __restrict__ x, const float* __restrict__ w_sel,
    const float* __restrict__ b_sel, float* __restrict__ xs)
{
  const int t = blockIdx.x, k = threadIdx.x;
  float s = 0.f;
  for (int b = 0; b < Bsz; b++) s += x[((size_t)b * Tsz + t) * Isz + k];
  float pr[3];
  #pragma unroll
  for (int qq = 0; qq < 3; qq++) pr[qq] = s * w_sel[qq * (Hsz + Isz) + Hsz + k];
  #pragma unroll
  for (int off = 32; off; off >>= 1)
    #pragma unroll
    for (int qq = 0; qq < 3; qq++) pr[qq] += __shfl_xor(pr[qq], off);
  __shared__ float red[4][3];
  const int wv = k >> 6, ln = k & 63;
  if (ln == 0) { red[wv][0] = pr[0]; red[wv][1] = pr[1]; red[wv][2] = pr[2]; }
  __syncthreads();
  if (k == 0) {
    #pragma unroll
    for (int qq = 0; qq < 3; qq++)
      xs[t * 3 + qq] = red[0][qq] + red[1][qq] + red[2][qq] + red[3][qq]
                      + (float)Bsz * b_sel[qq];
  }
}

// ---------------- serial selector chain ----------------
__global__ __launch_bounds__(256) void select_kernel(
    const float* __restrict__ score_h, const float* __restrict__ xs,
    int* __restrict__ cur)
{
  __shared__ int f[Tsz][3];
  const int tid = threadIdx.x;
  for (int u = tid; u < (Tsz - 1) * 3; u += 256) {
    const int t = 1 + u / 3, cc = u % 3;
    const float* sh = score_h + ((size_t)cc * Tsz + (t - 1)) * 3;
    const float* xr = xs + t * 3;
    const float v0 = sh[0] + xr[0];
    const float v1 = sh[1] + xr[1];
    const float v2 = sh[2] + xr[2];
    int best = 0; float bv = v0;
    if (v1 > bv) { bv = v1; best = 1; }
    if (v2 > bv) { bv = v2; best = 2; }
    f[t][cc] = best;
  }
  __syncthreads();
  if (tid == 0) {
    int cc = 0; cur[0] = 0;
    for (int t = 1; t < Tsz; t++) { cc = f[t][cc]; cur[t] = cc; }
  }
}

// ---------------- gather outputs (fp16 h -> fp32 out) ----------------
__global__ __launch_bounds__(256) void gather_out(
    const _Float16* __restrict__ Hh, const int* __restrict__ cur,
    float* __restrict__ out)
{
  const size_t idx = ((size_t)blockIdx.x * 256 + threadIdx.x) * 4;
  const size_t BTH = (size_t)Bsz * Tsz * Hsz;
  int b, t, h;
  if (idx < BTH) {
    b = (int)(idx >> 16);
    const int rem = (int)(idx & 65535);
    t = rem >> 8; h = rem & 255;
  } else {
    const size_t r2 = idx - BTH;
    b = (int)(r2 >> 8); h = (int)(r2 & 255); t = Tsz - 1;
  }
  const int cc = cur[t];
  const size_t g = (((size_t)cc * Mrows + (size_t)b * Tsz + t) * Hsz + h);
  union { ushort4 u; _Float16 hv[4]; } cv;
  cv.u = *(const ushort4*)(Hh + g);
  float4 v;
  v.x = (float)cv.hv[0]; v.y = (float)cv.hv[1];
  v.z = (float)cv.hv[2]; v.w = (float)cv.hv[3];
  *(float4*)(out + idx) = v;
}

extern "C" void kernel_launch(void* const* d_in, const int* in_sizes, int n_in,
                              void* d_out, int out_size, void* d_ws, size_t ws_size,
                              hipStream_t stream) {
  const float* x      = (const float*)d_in[0];
  const float* hidden = (const float*)d_in[1];
  const float* w_ih0  = (const float*)d_in[2];
  const float* b_ih0  = (const float*)d_in[3];
  const float* b_hh0  = (const float*)d_in[4];
  const float* w_ih   = (const float*)d_in[5];
  const float* b_ih   = (const float*)d_in[6];
  const float* b_hh   = (const float*)d_in[7];
  const float* w_lw   = (const float*)d_in[8];
  const float* b_lw   = (const float*)d_in[9];
  const float* w_sel  = (const float*)d_in[10];
  const float* b_sel  = (const float*)d_in[11];
  float* out = (float*)d_out;

  char* w = (char*)d_ws;
  const size_t HN = (size_t)3 * Mrows * 256;       // 25.2M
  const size_t XN = (size_t)Bsz * Tsz * Isz;       // 8.39M
  const size_t W0N = (size_t)3 * 768 * 256;        // 589824
  const size_t WLN = (size_t)3 * 3 * 768 * 256;    // 1769472
  _Float16* HA  = (_Float16*)w; w += HN * 2;
  _Float16* HB  = (_Float16*)w; w += HN * 2;
  _Float16* xh  = (_Float16*)w; w += XN * 2;
  _Float16* Wh0 = (_Float16*)w; w += W0N * 2;
  _Float16* WhL = (_Float16*)w; w += WLN * 2;
  float* e       = (float*)w; w += (size_t)3 * Tsz * Bsz * 16 * 4;
  float* p       = (float*)w; w += (size_t)3 * Tsz * Bsz * 12 * 4;
  float* score_h = (float*)w; w += (size_t)3 * Tsz * 3 * 4;
  float* xsb     = (float*)w; w += (size_t)Tsz * 3 * 4;
  int*   curb    = (int*)w;   w += (size_t)Tsz * 4;

  // fp32 -> fp16 conversions
  f32_to_f16<<<(int)(XN / 8 + 255) / 256, 256, 0, stream>>>(x, xh, (int)(XN / 8));
  f32_to_f16<<<(int)(W0N / 8 + 255) / 256, 256, 0, stream>>>(w_ih0, Wh0, (int)(W0N / 8));
  f32_to_f16<<<(int)(WLN / 8 + 255) / 256, 256, 0, stream>>>(w_ih, WhL, (int)(WLN / 8));

  // weight-stationary GEMM grid: (mseg, n-tile, cur)
  dim3 ggrid(64, 4, 3);

  // layer 0: A = xh (shared across cur)
  gemm_gru_f16<<<ggrid, 256, 0, stream>>>(
      xh, (size_t)0, Wh0, (size_t)768 * 256,
      b_ih0, (size_t)768, b_hh0, (size_t)768, HA);
  ep_tile<<<(3 * Mrows) / 64, 256, 0, stream>>>(HA, w_lw, w_sel, 0, e, p);

  const size_t wcur = (size_t)3 * 768 * 256;
  const size_t bst  = (size_t)3 * 768;
  _Float16* ping = HA; _Float16* pong = HB;
  for (int l = 1; l < 4; l++) {
    gemm_gru_f16<<<ggrid, 256, 0, stream>>>(
        ping, (size_t)Mrows * 256,
        WhL + (size_t)(l - 1) * 768 * 256, wcur,
        b_ih + (size_t)(l - 1) * 768, bst,
        b_hh + (size_t)(l - 1) * 768, bst, pong);
    ep_tile<<<(3 * Mrows) / 64, 256, 0, stream>>>(pong, w_lw, w_sel, l, e, p);
    _Float16* t1 = ping; ping = pong; pong = t1;
  }

  attn_finish<<<dim3(Tsz, 3), 128, 0, stream>>>(e, p, hidden, b_lw, score_h);
  xs_kernel<<<Tsz, 256, 0, stream>>>(x, w_sel, b_sel, xsb);
  select_kernel<<<1, 256, 0, stream>>>(score_h, xsb, curb);
  gather_out<<<8224, 256, 0, stream>>>(ping, curb, out);
}